// Round 19
// baseline (275.872 us; speedup 1.0000x reference)
//
#include <hip/hip_runtime.h>
#include <hip/hip_bf16.h>

typedef __bf16 bf16_t;
typedef __bf16 bf16x8 __attribute__((ext_vector_type(8)));
typedef float f32x4 __attribute__((ext_vector_type(4)));

#define B_ 8
#define LQ_ 2048
#define LK_ 2048
#define DM_ 1024

__device__ __forceinline__ void gload16(const void* g, void* l) {
  __builtin_amdgcn_global_load_lds(
      (const __attribute__((address_space(1))) void*)g,
      (__attribute__((address_space(3))) void*)l, 16, 0, 0);
}

// ------------- fused prep: x/keys/Wq f32->bf16 + V transpose -------------
__global__ __launch_bounds__(256) void prep_kernel(
    const float* __restrict__ x, const float* __restrict__ keys,
    const float* __restrict__ Wq, const float* __restrict__ vals,
    bf16_t* __restrict__ xbf, bf16_t* __restrict__ kbf,
    bf16_t* __restrict__ wqbf, bf16_t* __restrict__ vt) {
  const int bid = blockIdx.x;
  const int tid = threadIdx.x;
  if (bid < 2176) {
    const float* in;
    bf16_t* out;
    int n8, i0, nb;
    if (bid < 1024) {
      in = x; out = xbf; n8 = (B_ * LQ_ * DM_) / 8; i0 = bid; nb = 1024;
    } else if (bid < 2048) {
      in = keys; out = kbf; n8 = (B_ * LK_ * DM_) / 8; i0 = bid - 1024; nb = 1024;
    } else {
      in = Wq; out = wqbf; n8 = (DM_ * DM_) / 8; i0 = bid - 2048; nb = 128;
    }
    int stride = nb * 256;
    for (int i = i0 * 256 + tid; i < n8; i += stride) {
      const float4* p = reinterpret_cast<const float4*>(in) + (size_t)i * 2;
      float4 a = p[0], b = p[1];
      bf16x8 o;
      o[0] = (bf16_t)a.x; o[1] = (bf16_t)a.y; o[2] = (bf16_t)a.z; o[3] = (bf16_t)a.w;
      o[4] = (bf16_t)b.x; o[5] = (bf16_t)b.y; o[6] = (bf16_t)b.z; o[7] = (bf16_t)b.w;
      *reinterpret_cast<bf16x8*>(out + (size_t)i * 8) = o;
    }
  } else {
    __shared__ bf16_t tile[64][65];
    const int t = bid - 2176;            // 0..4095
    const int k0 = (t & 31) * 64;
    const int d0 = ((t >> 5) & 15) * 64;
    const int b = t >> 9;
    const float* src = vals + ((size_t)b * LK_ + k0) * DM_ + d0;
    const int lr = tid >> 4;
    const int lc = (tid & 15) * 4;
#pragma unroll
    for (int rr = 0; rr < 64; rr += 16) {
      float4 v = *reinterpret_cast<const float4*>(src + (size_t)(rr + lr) * DM_ + lc);
      bf16_t* d = &tile[rr + lr][lc];
      d[0] = (bf16_t)v.x; d[1] = (bf16_t)v.y; d[2] = (bf16_t)v.z; d[3] = (bf16_t)v.w;
    }
    __syncthreads();
    bf16_t* dst = vt + ((size_t)b * DM_ + d0) * LK_ + k0;
    const int sd = tid >> 3;
    const int sk = (tid & 7) * 8;
#pragma unroll
    for (int pass = 0; pass < 2; ++pass) {
      const int d = pass * 32 + sd;
      bf16x8 o;
#pragma unroll
      for (int j = 0; j < 8; ++j) o[j] = tile[sk + j][d];
      *reinterpret_cast<bf16x8*>(dst + (size_t)d * LK_ + sk) = o;
    }
  }
}

// -------- 128x128 GEMM, 3 blocks/CU co-residency experiment -----------
// All prior structures ran 1 block/CU: the 8 waves convoy on shared
// barriers, so the CU's LDS and MFMA pipes strictly alternate (additive;
// MfmaUtil ~35% across 7 structures). Here: 128x128 tile, BK=32, 4 waves
// (2x2, 64x64/wave, acc=64 AGPR), 3 LDS bufs = 48KB -> 3 independent
// blocks/CU; block A's MFMA phase overlaps block B's LDS phase (m114
// co-scheduling). Stage-ahead-2, vmcnt(4) (one full iter of HBM cover),
// 1 barrier/iter. Invariants: drain-before-barrier, read-after-barrier;
// stage target buf[(t+2)%3] was consumed at t-1 (barrier-protected).
// Swizzle: r12-verified BK=32 pattern, phys_slot = slot ^ ((row>>1)&3).
// MODE 0: C bf16, C += bias[col]
// MODE 1: C bf16, exp(C/32+mask); rowsum partials -> extra2[bz][16][2048]
// MODE 2: C f32, C = acc / rowsum (partials summed+inverted in epilogue)
#define BARX __builtin_amdgcn_s_barrier()
#define PRIO1 __builtin_amdgcn_s_setprio(1)
#define PRIO0 __builtin_amdgcn_s_setprio(0)
#define VM4 asm volatile("s_waitcnt vmcnt(4)" ::: "memory")
#define VM0 asm volatile("s_waitcnt vmcnt(0)" ::: "memory")

template <int MODE>
__global__ __launch_bounds__(256, 3) void gemm128(
    const bf16_t* __restrict__ A, const bf16_t* __restrict__ Bm,
    void* __restrict__ Cv, const float* __restrict__ extra,
    float* __restrict__ extra2,
    int N, int K, long sA, long sB, long sC, long sE, int gxs, int gys) {
  __shared__ bf16_t lds[24576];  // 3 bufs x (A 8KB + B 8KB) = 48 KiB

  const int tid = threadIdx.x;
  const int lane = tid & 63;
  const int wave = tid >> 6;

  // XCD-aware bijective block swizzle (gridDim.x % 8 == 0 for all grids)
  const int nwg = gridDim.x;
  const int lin = blockIdx.x;
  const int cpx = nwg >> 3;
  const int swz = (lin & 7) * cpx + (lin >> 3);
  const int gx = 1 << gxs;
  const int bx = swz & (gx - 1);
  const int rem = swz >> gxs;
  const int by = rem & ((1 << gys) - 1);
  const int bz = rem >> gys;

  const bf16_t* Ab = A + (long)bz * sA + (long)(by * 128) * K;
  const bf16_t* Bb = Bm + (long)bz * sB + (long)(bx * 128) * K;

  // staging: chunk c = tid (rows 0..63) and twin +64 rows; phys slot c&3,
  // source col = (slot ^ q(row))*8 elems, q(row) = (row>>1)&3 (involution).
  const int r0 = tid >> 2;                              // 0..63
  const int scol = ((tid & 3) ^ ((r0 >> 1) & 3)) * 8;   // pre-swizzled

  auto STG = [&](int t, int bufI) {
    bf16_t* base = lds + bufI * 8192 + wave * 512;  // wave-uniform dest
    const bf16_t* gA = Ab + (long)r0 * K + t * 32 + scol;
    const bf16_t* gB = Bb + (long)r0 * K + t * 32 + scol;
    gload16(gA, base);                        // A rows 0-63
    gload16(gA + (long)64 * K, base + 2048);  // A rows 64-127 (q invariant)
    gload16(gB, base + 4096);                 // B rows 0-63
    gload16(gB + (long)64 * K, base + 6144);  // B rows 64-127
  };

  // fragment read geometry (r12-verified conflict-free pattern)
  const int wr = wave >> 1;   // 0..1
  const int wc = wave & 1;    // 0..1
  const int fr = lane & 15;
  const int g = lane >> 4;    // k-granule 0..3
  const int sp = (g ^ ((fr >> 1) & 3)) * 16;  // swizzled slot bytes
  const char* ldsc = (const char*)lds;
  const char* pa = ldsc + (wr * 64 + fr) * 64 + sp;          // + m*1024
  const char* pb = ldsc + 8192 + (wc * 64 + fr) * 64 + sp;   // + n*1024

  f32x4 acc[4][4] = {};
  bf16x8 aF[4], bF[4];

  const int NT = K >> 5;  // BK=32 tiles (32 or 64 here)

  // prologue: t0 -> buf0, t1 -> buf1; drain t0, keep t1 in flight
  STG(0, 0); STG(1, 1);
  VM4; BARX;

  int cur = 0, stg = 2;
  for (int t = 0; t < NT; ++t) {
    if (t + 2 < NT) STG(t + 2, stg);  // buf consumed at t-1: WAR-safe
    const int cb = cur * 16384;       // byte offset of current buf
#pragma unroll
    for (int m = 0; m < 4; ++m)
      aF[m] = *(const bf16x8*)(pa + cb + m * 1024);
#pragma unroll
    for (int n = 0; n < 4; ++n)
      bF[n] = *(const bf16x8*)(pb + cb + n * 1024);
    PRIO1;
#pragma unroll
    for (int m = 0; m < 4; ++m)
#pragma unroll
      for (int n = 0; n < 4; ++n)
        acc[m][n] = __builtin_amdgcn_mfma_f32_16x16x32_bf16(
            aF[m], bF[n], acc[m][n], 0, 0, 0);
    PRIO0;
    if (t + 2 < NT)      { VM4; }   // t+1's loads landed (issued iter t-1)
    else if (t + 1 < NT) { VM0; }   // tail: drain last tile
    BARX;
    cur = cur == 2 ? 0 : cur + 1;
    stg = stg == 2 ? 0 : stg + 1;
  }
  // loop exits drained + barrier-aligned -> LDS reusable.

  // epilogue
  const int cn = lane & 15;
  const int rr = (lane >> 4) * 4;
  const int row0 = by * 128 + wr * 64;
  const int col0 = bx * 128 + wc * 64;

  if (MODE == 0) {
    bf16_t* C = (bf16_t*)Cv;
#pragma unroll
    for (int m = 0; m < 4; ++m) {
      const int row = row0 + m * 16 + rr;
#pragma unroll
      for (int n = 0; n < 4; ++n) {
        const int col = col0 + n * 16 + cn;
        float bias = extra[col];
#pragma unroll
        for (int j = 0; j < 4; ++j)
          C[(long)(row + j) * N + col] = (bf16_t)(acc[m][n][j] + bias);
      }
    }
  } else if (MODE == 1) {
    bf16_t* C = (bf16_t*)Cv + (long)bz * sC;
    float* lds_f = (float*)lds;  // [wc][128 rows]
#pragma unroll
    for (int m = 0; m < 4; ++m) {
      const int row = row0 + m * 16 + rr;
      float sm0 = 0.f, sm1 = 0.f, sm2 = 0.f, sm3 = 0.f;
#pragma unroll
      for (int n = 0; n < 4; ++n) {
        const int col = col0 + n * 16 + cn;
        float mk = extra[(long)bz * sE + col];
        float e0 = __expf(acc[m][n][0] * 0.03125f + mk);
        float e1 = __expf(acc[m][n][1] * 0.03125f + mk);
        float e2 = __expf(acc[m][n][2] * 0.03125f + mk);
        float e3 = __expf(acc[m][n][3] * 0.03125f + mk);
        C[(long)(row + 0) * N + col] = (bf16_t)e0;
        C[(long)(row + 1) * N + col] = (bf16_t)e1;
        C[(long)(row + 2) * N + col] = (bf16_t)e2;
        C[(long)(row + 3) * N + col] = (bf16_t)e3;
        sm0 += e0; sm1 += e1; sm2 += e2; sm3 += e3;
      }
#pragma unroll
      for (int w = 1; w < 16; w <<= 1) {
        sm0 += __shfl_xor(sm0, w, 64);
        sm1 += __shfl_xor(sm1, w, 64);
        sm2 += __shfl_xor(sm2, w, 64);
        sm3 += __shfl_xor(sm3, w, 64);
      }
      if (cn == 0) {
        const int br = wr * 64 + m * 16 + (lane >> 4) * 4;
        lds_f[wc * 128 + br + 0] = sm0;
        lds_f[wc * 128 + br + 1] = sm1;
        lds_f[wc * 128 + br + 2] = sm2;
        lds_f[wc * 128 + br + 3] = sm3;
      }
    }
    __syncthreads();
    if (tid < 128) {
      float s2 = lds_f[tid] + lds_f[128 + tid];
      extra2[((long)bz * 16 + bx) * 2048 + by * 128 + tid] = s2;
    }
  } else {
    float* C = (float*)Cv + (long)bz * sC;
    float* lds_rs = (float*)lds;
    if (tid < 128) {
      const float* pb2 = extra + (long)bz * 16 * 2048 + by * 128 + tid;
      float s = 0.f;
#pragma unroll
      for (int cb2 = 0; cb2 < 16; ++cb2) s += pb2[(long)cb2 * 2048];
      lds_rs[tid] = 1.0f / s;
    }
    __syncthreads();
#pragma unroll
    for (int m = 0; m < 4; ++m) {
      const int row = row0 + m * 16 + rr;
      const int rl = wr * 64 + m * 16 + rr;
      float i0 = lds_rs[rl + 0], i1 = lds_rs[rl + 1];
      float i2 = lds_rs[rl + 2], i3 = lds_rs[rl + 3];
#pragma unroll
      for (int n = 0; n < 4; ++n) {
        const int col = col0 + n * 16 + cn;
        C[(long)(row + 0) * N + col] = acc[m][n][0] * i0;
        C[(long)(row + 1) * N + col] = acc[m][n][1] * i1;
        C[(long)(row + 2) * N + col] = acc[m][n][2] * i2;
        C[(long)(row + 3) * N + col] = acc[m][n][3] * i3;
      }
    }
  }
}

extern "C" void kernel_launch(void* const* d_in, const int* in_sizes, int n_in,
                              void* d_out, int out_size, void* d_ws, size_t ws_size,
                              hipStream_t stream) {
  const float* x    = (const float*)d_in[0];
  const float* mask = (const float*)d_in[1];
  const float* keys = (const float*)d_in[2];
  const float* vals = (const float*)d_in[3];
  const float* Wq   = (const float*)d_in[4];
  const float* bq   = (const float*)d_in[5];
  float* out = (float*)d_out;

  char* ws = (char*)d_ws;
  bf16_t* kbf    = (bf16_t*)(ws);
  bf16_t* vt     = (bf16_t*)(ws + 33554432);
  bf16_t* qbf    = (bf16_t*)(ws + 67108864);
  bf16_t* logits = (bf16_t*)(ws + 100663296);  // holds p_unnorm = exp(logit)
  bf16_t* xbf    = logits;  // reused: x_bf dead before logits are written
  bf16_t* wqbf   = (bf16_t*)(ws + 167772160);
  // wqbf region (2 MB) dead after Q-proj; pbuf [8][16][2048] f32 = 2 MB:
  float* pbuf = (float*)(ws + 167772160);

  // 1. fused prep: converts + V transpose
  prep_kernel<<<6272, 256, 0, stream>>>(x, keys, Wq, vals, xbf, kbf, wqbf, vt);

  // 2. Q = x @ Wq^T + bq   (M=16384, N=1024, K=1024) grid 8x128 = 1024
  gemm128<0><<<1024, 256, 0, stream>>>(
      xbf, wqbf, qbf, bq, nullptr, DM_, DM_, 0, 0, 0, 0, 3, 7);

  // 3. p_unnorm = exp(Q@K^T/32 + mask) + rowsum partials; 16x16x8 = 2048
  gemm128<1><<<2048, 256, 0, stream>>>(
      qbf, kbf, logits, mask, pbuf, LK_, DM_,
      (long)LQ_ * DM_, (long)LK_ * DM_, (long)LQ_ * LK_, LK_, 4, 4);

  // 4. out = (P @ Vt^T) / rowsum(P); finalize fused; 8x16x8 = 1024
  gemm128<2><<<1024, 256, 0, stream>>>(
      logits, vt, out, pbuf, nullptr, DM_, LK_,
      (long)LQ_ * LK_, (long)DM_ * LK_, (long)LQ_ * DM_, 0, 3, 4);
}